// Round 8
// baseline (1078.866 us; speedup 1.0000x reference)
//
#include <hip/hip_runtime.h>
#include <cstdint>
#include <cstddef>

#define Tsz 512
#define TC  32          // steps per chunk
#define NCH 16          // Tsz / TC

typedef _Float16 f16;
typedef _Float16 half8_t __attribute__((ext_vector_type(8)));
typedef _Float16 half4_t __attribute__((ext_vector_type(4)));
typedef float float4_t __attribute__((ext_vector_type(4)));

__device__ __forceinline__ float fast_exp2(float x) {
  float r;
  asm("v_exp_f32 %0, %1" : "=v"(r) : "v"(x));
  return r;
}
// Opaque pin: value becomes asm-defined -> compiler cannot rematerialize it
// by re-loading from memory inside the loop (round-7-proven: 1828->1069 us).
__device__ __forceinline__ void pin(half8_t& v) { asm("" : "+v"(v)); }

#define BARRIER_LG asm volatile("s_waitcnt lgkmcnt(0)\n\ts_barrier" ::: "memory")

// One layer-chunk: TC steps of layer LAYER on one 16-row batch tile.
// 512 threads = 8 waves; wave owns 32 output cols (2 MFMA col-tiles).
// Weights register-resident (pinned). h double-buffered in LDS -> ONE
// lgkm-only barrier/step. Inputs (x or prev-layer ring) are prefetched
// DIRECTLY into registers 2 steps ahead (no LDS staging hop) -- halves
// the per-step LDS read convoy (round-7 bottleneck).
template<int LAYER>
__device__ __forceinline__ void layer_body(
    char* const smem, const int chunk, const int tile,
    const float* __restrict__ x,     // LAYER==0 input
    const f16* inbuf,                // LAYER>=1 input ring (image layout)
    const f16* __restrict__ wih_h, const f16* __restrict__ whh_h,
    const float* __restrict__ biasc,
    f16* outbuf,                     // LAYER<2 output ring (image layout)
    f16* st)                         // per-layer carried h (image layout)
{
  constexpr int NIN = (LAYER == 0) ? 2 : 8;
  char* const h_lds = smem;          // 2 x 8192: [32 chunks][16 rows][16B] images

  const int tid  = threadIdx.x;
  const int lane = tid & 63;
  const int wave = tid >> 6;
  const int m    = lane & 15;
  const int q    = lane >> 4;
  const int lo   = m * 16;
  const int t0   = chunk * TC;
  const int slot = chunk & 1;        // global ring slot for in/out bufs

  // one-time weight load (B-operand: B[k][n]=W[n][k], n=lane&15, k=q*8+i), then PIN
  half8_t whh[2][8], wih[2][NIN];
  float bias[2];
#pragma unroll
  for (int jt = 0; jt < 2; ++jt) {
    const int j = wave * 32 + jt * 16 + m;
    bias[jt] = biasc[LAYER * 256 + j];
#pragma unroll
    for (int c = 0; c < 8; ++c)
      whh[jt][c] = *(const half8_t*)(whh_h + j * 256 + c * 32 + q * 8);
#pragma unroll
    for (int c = 0; c < NIN; ++c)
      wih[jt][c] = *(const half8_t*)(wih_h + j * (NIN * 32) + c * 32 + q * 8);
  }
#pragma unroll
  for (int jt = 0; jt < 2; ++jt) {
#pragma unroll
    for (int c = 0; c < 8; ++c) pin(whh[jt][c]);
#pragma unroll
    for (int c = 0; c < NIN; ++c) pin(wih[jt][c]);
  }

  // h_{t0-1}: zeros on chunk 0, else carried state (image copy)
  if (chunk == 0)
    *(float4_t*)(h_lds + tid * 16) = float4_t{0.f, 0.f, 0.f, 0.f};
  else
    *(float4_t*)(h_lds + tid * 16) = *(const float4_t*)((const char*)st + tile * 8192 + tid * 16);

  // ---- input register prefetch, 2-deep ping-pong ----
  float4_t  xp[2][4];                // LAYER0: f32 x rows
  half8_t   xq[2][8];                // LAYER>=1: fragment-image direct loads
  auto xload = [&](int t, float4_t* d) {
    const int tc = (t > Tsz - 1) ? (Tsz - 1) : t;
    const float* base = x + ((size_t)(tile * 16 + m) * Tsz + tc) * 64 + q * 8;
    d[0] = *(const float4_t*)base;        d[1] = *(const float4_t*)(base + 4);
    d[2] = *(const float4_t*)(base + 32); d[3] = *(const float4_t*)(base + 36);
  };
  auto xqload = [&](int tl, half8_t* d) {
    const int tn = (tl > TC - 1) ? (TC - 1) : tl;
    const char* gb = (const char*)inbuf + (((size_t)(tile * 2 + slot) * TC + tn) << 13) + lo;
#pragma unroll
    for (int c = 0; c < 8; ++c)
      d[c] = *(const half8_t*)(gb + (c * 4 + q) * 256);   // global_load_dwordx4
  };

  if constexpr (LAYER == 0) { xload(t0, xp[0]); xload(t0 + 1, xp[1]); }
  else                      { xqload(0, xq[0]); xqload(1, xq[1]); }
  BARRIER_LG;                        // h image visible; input waits compiler-managed

#pragma unroll 4
  for (int tl = 0; tl < TC; ++tl) {
    char* cur = h_lds + (tl & 1) * 8192;
    char* nxt = h_lds + ((tl + 1) & 1) * 8192;

    // A-fragments from registers; refill just-consumed slot for tl+2
    half8_t xf[NIN];
    if constexpr (LAYER == 0) {
      const float4_t* xr = xp[tl & 1];
#pragma unroll
      for (int c = 0; c < 2; ++c)
#pragma unroll
        for (int u = 0; u < 8; ++u) xf[c][u] = (f16)xr[c * 2 + (u >> 2)][u & 3];
      xload(t0 + tl + 2, xp[tl & 1]);
    } else {
#pragma unroll
      for (int c = 0; c < 8; ++c) xf[c] = xq[tl & 1][c];
      xqload(tl + 2, xq[tl & 1]);
    }
    half8_t hf[8];
#pragma unroll
    for (int c = 0; c < 8; ++c) hf[c] = *(const half8_t*)(cur + (c * 4 + q) * 256 + lo);

    // two independent MFMA chains per col-tile
    float4_t acc[2];
#pragma unroll
    for (int jt = 0; jt < 2; ++jt) {
      float4_t a0 = {bias[jt], bias[jt], bias[jt], bias[jt]};
      float4_t a1 = {0.f, 0.f, 0.f, 0.f};
#pragma unroll
      for (int c = 0; c < NIN; ++c)
        a0 = __builtin_amdgcn_mfma_f32_16x16x32_f16(xf[c], wih[jt][c], a0, 0, 0, 0);
#pragma unroll
      for (int c = 0; c < 8; ++c)
        a1 = __builtin_amdgcn_mfma_f32_16x16x32_f16(hf[c], whh[jt][c], a1, 0, 0, 0);
      acc[jt] = a0 + a1;
    }

    // epilogue: tanh -> h(t) image in nxt. C/D layout: col=lane&15, row=q*4+r.
    // tanh(x) = 1 - 2/(1+e^{2x}); raw v_exp_f32 (inf-safe at both ends).
#pragma unroll
    for (int jt = 0; jt < 2; ++jt) {
      const int j = wave * 32 + jt * 16 + m;
#pragma unroll
      for (int r = 0; r < 4; ++r) {
        const float e    = fast_exp2(acc[jt][r] * 2.8853900817779268f);   // 2*log2(e)*x
        const float hval = 1.0f - 2.0f * __builtin_amdgcn_rcpf(1.0f + e);
        const int b = q * 4 + r;
        *(f16*)(nxt + (j >> 3) * 256 + b * 16 + (j & 7) * 2) = (f16)hval;
      }
    }

    BARRIER_LG;                      // h(t) writes visible; cur reads drained

    if constexpr (LAYER < 2) {       // coalesced image copy of h(t) to global ring
      char* gp = (char*)outbuf + (((size_t)(tile * 2 + slot) * TC + tl) << 13) + tid * 16;
      *(float4_t*)gp = *(const float4_t*)(nxt + tid * 16);
    }
  }

  // persist h (TC even -> final h image is buffer 0)
  *(float4_t*)((char*)st + tile * 8192 + tid * 16) = *(const float4_t*)(h_lds + tid * 16);
}

__global__ __launch_bounds__(512, 1)
void rnn_chunk_kernel(const float* __restrict__ x,
                      f16* bufA, f16* bufB,
                      const f16* __restrict__ wih0h, const f16* __restrict__ whh0h,
                      const f16* __restrict__ wih1h, const f16* __restrict__ whh1h,
                      const f16* __restrict__ wih2h, const f16* __restrict__ whh2h,
                      const float* __restrict__ biasc,
                      f16* st0, f16* st1, f16* st2, int k)
{
  __shared__ __align__(16) char smem[16384];
  const int layer = blockIdx.x >> 5;
  const int tile  = blockIdx.x & 31;
  const int chunk = k - layer;
  if (chunk < 0 || chunk >= NCH) return;
  if (layer == 0)
    layer_body<0>(smem, chunk, tile, x, nullptr, wih0h, whh0h, biasc, bufA, st0);
  else if (layer == 1)
    layer_body<1>(smem, chunk, tile, nullptr, bufA, wih1h, whh1h, biasc, bufB, st1);
  else
    layer_body<2>(smem, chunk, tile, nullptr, bufB, wih2h, whh2h, biasc, nullptr, st2);
}

// one-time weight convert f32->f16 (row-major preserved) + bias combine
__global__ void prep_kernel(const float* __restrict__ wih0, const float* __restrict__ whh0,
                            const float* __restrict__ bih0, const float* __restrict__ bhh0,
                            const float* __restrict__ wih1, const float* __restrict__ whh1,
                            const float* __restrict__ bih1, const float* __restrict__ bhh1,
                            const float* __restrict__ wih2, const float* __restrict__ whh2,
                            const float* __restrict__ bih2, const float* __restrict__ bhh2,
                            f16* wih0h, f16* whh0h, f16* wih1h, f16* whh1h,
                            f16* wih2h, f16* whh2h, float* biasc)
{
  const int i = blockIdx.x * 256 + threadIdx.x;
  if      (i < 16384)  wih0h[i]          = (f16)wih0[i];
  else if (i < 81920)  whh0h[i - 16384]  = (f16)whh0[i - 16384];
  else if (i < 147456) wih1h[i - 81920]  = (f16)wih1[i - 81920];
  else if (i < 212992) whh1h[i - 147456] = (f16)whh1[i - 147456];
  else if (i < 278528) wih2h[i - 212992] = (f16)wih2[i - 212992];
  else if (i < 344064) whh2h[i - 278528] = (f16)whh2[i - 278528];
  else if (i < 344320) biasc[i - 344064]       = bih0[i - 344064] + bhh0[i - 344064];
  else if (i < 344576) biasc[256 + i - 344320] = bih1[i - 344320] + bhh1[i - 344320];
  else if (i < 344832) biasc[512 + i - 344576] = bih2[i - 344576] + bhh2[i - 344576];
}

__global__ void fc_kernel(const f16* __restrict__ st2, const float* __restrict__ w_fc,
                          const float* __restrict__ b_fc, float* __restrict__ outp) {
  const int b = blockIdx.x;            // 512
  const int lane = threadIdx.x;        // 64
  const int tile = b >> 4, bl = b & 15;
  const int j = lane * 4;              // 4 consecutive cols; contiguous 8B in image
  const char* hp = (const char*)st2 + tile * 8192 + (j >> 3) * 256 + bl * 16 + (j & 7) * 2;
  const half4_t hv = *(const half4_t*)hp;
  const float4_t w = *(const float4_t*)(w_fc + j);
  float s = (float)hv[0] * w[0] + (float)hv[1] * w[1] + (float)hv[2] * w[2] + (float)hv[3] * w[3];
#pragma unroll
  for (int off = 32; off > 0; off >>= 1) s += __shfl_down(s, off, 64);
  if (lane == 0) outp[b] = s + b_fc[0];
}

extern "C" void kernel_launch(void* const* d_in, const int* in_sizes, int n_in,
                              void* d_out, int out_size, void* d_ws, size_t ws_size,
                              hipStream_t stream) {
  const float* x     = (const float*)d_in[0];
  const float* w_ih0 = (const float*)d_in[1];
  const float* w_hh0 = (const float*)d_in[2];
  const float* b_ih0 = (const float*)d_in[3];
  const float* b_hh0 = (const float*)d_in[4];
  const float* w_ih1 = (const float*)d_in[5];
  const float* w_hh1 = (const float*)d_in[6];
  const float* b_ih1 = (const float*)d_in[7];
  const float* b_hh1 = (const float*)d_in[8];
  const float* w_ih2 = (const float*)d_in[9];
  const float* w_hh2 = (const float*)d_in[10];
  const float* b_ih2 = (const float*)d_in[11];
  const float* b_hh2 = (const float*)d_in[12];
  const float* w_fc  = (const float*)d_in[13];
  const float* b_fc  = (const float*)d_in[14];

  // ws layout, 35.0 MB total (round-3 proved ws_size >= 269,484,032):
  char* ws = (char*)d_ws;
  f16* bufA   = (f16*)(ws);                   // 16,777,216  L0->L1 ring (32 tiles x 2 slots x 32 x 8KB)
  f16* bufB   = (f16*)(ws + 16777216);        // 16,777,216  L1->L2 ring
  f16* st0    = (f16*)(ws + 33554432);        //    262,144  carried h, layer 0 (image)
  f16* st1    = (f16*)(ws + 33816576);        //    262,144
  f16* st2    = (f16*)(ws + 34078720);        //    262,144
  f16* wih0h  = (f16*)(ws + 34340864);        //     32,768
  f16* whh0h  = (f16*)(ws + 34373632);        //    131,072
  f16* wih1h  = (f16*)(ws + 34504704);        //    131,072
  f16* whh1h  = (f16*)(ws + 34635776);        //    131,072
  f16* wih2h  = (f16*)(ws + 34766848);        //    131,072
  f16* whh2h  = (f16*)(ws + 34897920);        //    131,072
  float* biasc = (float*)(ws + 35028992);     //      3,072

  prep_kernel<<<1347, 256, 0, stream>>>(w_ih0, w_hh0, b_ih0, b_hh0,
                                        w_ih1, w_hh1, b_ih1, b_hh1,
                                        w_ih2, w_hh2, b_ih2, b_hh2,
                                        wih0h, whh0h, wih1h, whh1h, wih2h, whh2h, biasc);
  // time-skewed layer pipeline: launch k runs L0@chunk k, L1@k-1, L2@k-2.
  // Kernel boundaries provide the producer->consumer ordering.
  for (int k = 0; k < NCH + 2; ++k)
    rnn_chunk_kernel<<<96, 512, 0, stream>>>(x, bufA, bufB,
                                             wih0h, whh0h, wih1h, whh1h, wih2h, whh2h,
                                             biasc, st0, st1, st2, k);
  fc_kernel<<<512, 64, 0, stream>>>(st2, w_fc, b_fc, (float*)d_out);
}

// Round 9
// 1031.700 us; speedup vs baseline: 1.0457x; 1.0457x over previous
//
#include <hip/hip_runtime.h>
#include <cstdint>
#include <cstddef>

#define Tsz 512
#define TC  32          // steps per chunk
#define NCH 16          // Tsz / TC

typedef _Float16 f16;
typedef _Float16 half8_t __attribute__((ext_vector_type(8)));
typedef _Float16 half4_t __attribute__((ext_vector_type(4)));
typedef float float4_t __attribute__((ext_vector_type(4)));

__device__ __forceinline__ float fast_exp2(float x) {
  float r; asm("v_exp_f32 %0, %1" : "=v"(r) : "v"(x)); return r;
}
// Opaque pin (round-7-proven): forbids remat-by-reload of weight fragments.
__device__ __forceinline__ void pin(half8_t& v) { asm("" : "+v"(v)); }

#define BARRIER_LG asm volatile("s_waitcnt lgkmcnt(0)\n\ts_barrier" ::: "memory")

// P layout (pre-activation, f32, MFMA C-layout): per (tile,slot,t): 256 cols x
// 16 rows; 64B per col. Thread (q) reads/writes float4 rows q*4..q*4+3.
__device__ __forceinline__ size_t poff(int tile, int slot, int t, int j, int q) {
  return (((size_t)((tile * 2 + slot) * TC + t) * 256 + j) << 6) + ((size_t)q << 4);
}

// ---- layers 0,1: rec (h-GEMM from P) + fused pre-GEMM of NEXT layer's P ----
template<int LAYER>
__device__ __forceinline__ void rec01_body(
    char* const smem, const int chunk, const int tile,
    const float* __restrict__ Pin, float* __restrict__ Pout,
    const f16* __restrict__ whh_h, const f16* __restrict__ wihn_h,
    const float* __restrict__ biasc, f16* __restrict__ st)
{
  char* const h_lds = smem;            // 2 x 8192: [32 chunks][16 rows][16B]
  const int tid  = threadIdx.x;
  const int lane = tid & 63;
  const int wave = tid >> 6;
  const int m    = lane & 15;
  const int q    = lane >> 4;
  const int lo   = m * 16;
  const int slot = chunk & 1;

  half8_t whh[2][8], wihn[2][8];
  float biasn[2];
#pragma unroll
  for (int jt = 0; jt < 2; ++jt) {
    const int j = wave * 32 + jt * 16 + m;
    biasn[jt] = biasc[(LAYER + 1) * 256 + j];
#pragma unroll
    for (int c = 0; c < 8; ++c) whh[jt][c]  = *(const half8_t*)(whh_h  + j * 256 + c * 32 + q * 8);
#pragma unroll
    for (int c = 0; c < 8; ++c) wihn[jt][c] = *(const half8_t*)(wihn_h + j * 256 + c * 32 + q * 8);
  }
#pragma unroll
  for (int jt = 0; jt < 2; ++jt) {
#pragma unroll
    for (int c = 0; c < 8; ++c) { pin(whh[jt][c]); pin(wihn[jt][c]); }
  }

  if (chunk == 0)
    *(float4_t*)(h_lds + tid * 16) = float4_t{0.f, 0.f, 0.f, 0.f};
  else
    *(float4_t*)(h_lds + tid * 16) = *(const float4_t*)((const char*)st + tile * 8192 + tid * 16);

  // P prefetch, 2-deep ping-pong (2 x dwordx4 per thread per step)
  float4_t pld[2][2];
  auto pload = [&](int tl, float4_t* d) {
    const int tn = (tl > TC - 1) ? (TC - 1) : tl;
    const char* gb = (const char*)Pin + poff(tile, slot, tn, wave * 32 + m, q);
    d[0] = *(const float4_t*)gb;
    d[1] = *(const float4_t*)(gb + 1024);  // jt=1: j+16 -> +16*64B
  };
  pload(0, pld[0]); pload(1, pld[1]);
  BARRIER_LG;                          // h image visible

#pragma unroll 4
  for (int tl = 0; tl < TC; ++tl) {
    char* cur = h_lds + (tl & 1) * 8192;
    char* nxt = h_lds + ((tl + 1) & 1) * 8192;

    half8_t hf[8];
#pragma unroll
    for (int c = 0; c < 8; ++c) hf[c] = *(const half8_t*)(cur + (c * 4 + q) * 256 + lo);

    // rec: acc = P(t) + h(t-1) @ Whh^T
    float4_t acc[2];
#pragma unroll
    for (int jt = 0; jt < 2; ++jt) {
      float4_t a = pld[tl & 1][jt];
#pragma unroll
      for (int c = 0; c < 8; ++c)
        a = __builtin_amdgcn_mfma_f32_16x16x32_f16(hf[c], whh[jt][c], a, 0, 0, 0);
      acc[jt] = a;
    }
    pload(tl + 2, pld[tl & 1]);        // refill just-consumed slot

    // fused pre for next layer, row tl-1 (hf == h(tl-1)); row TC-1 in epilogue.
    // tl==0's row belongs to previous chunk (done by its epilogue).
    if (tl >= 1) {
#pragma unroll
      for (int jt = 0; jt < 2; ++jt) {
        float4_t b = {biasn[jt], biasn[jt], biasn[jt], biasn[jt]};
#pragma unroll
        for (int c = 0; c < 8; ++c)
          b = __builtin_amdgcn_mfma_f32_16x16x32_f16(hf[c], wihn[jt][c], b, 0, 0, 0);
        *(float4_t*)((char*)Pout + poff(tile, slot, tl - 1, wave * 32 + jt * 16 + m, q)) = b;
      }
    }

    // tanh -> h(t) image. C/D layout: col=lane&15, row=q*4+r.
#pragma unroll
    for (int jt = 0; jt < 2; ++jt) {
      const int j = wave * 32 + jt * 16 + m;
#pragma unroll
      for (int r = 0; r < 4; ++r) {
        const float e  = fast_exp2(acc[jt][r] * 2.8853900817779268f);   // 2*log2(e)*x
        const float hv = 1.0f - 2.0f * __builtin_amdgcn_rcpf(1.0f + e);
        const int b = q * 4 + r;
        *(f16*)(nxt + (j >> 3) * 256 + b * 16 + (j & 7) * 2) = (f16)hv;
      }
    }
    BARRIER_LG;                        // one barrier/step (lgkm only)
  }

  // epilogue: pre for row TC-1 from final h image (buffer 0)
  {
    half8_t hf[8];
#pragma unroll
    for (int c = 0; c < 8; ++c) hf[c] = *(const half8_t*)(h_lds + (c * 4 + q) * 256 + lo);
#pragma unroll
    for (int jt = 0; jt < 2; ++jt) {
      float4_t b = {biasn[jt], biasn[jt], biasn[jt], biasn[jt]};
#pragma unroll
      for (int c = 0; c < 8; ++c)
        b = __builtin_amdgcn_mfma_f32_16x16x32_f16(hf[c], wihn[jt][c], b, 0, 0, 0);
      *(float4_t*)((char*)Pout + poff(tile, slot, TC - 1, wave * 32 + jt * 16 + m, q)) = b;
    }
  }
  *(float4_t*)((char*)st + tile * 8192 + tid * 16) = *(const float4_t*)(h_lds + tid * 16);
}

// ---- layer 2: rec (from P2) + pre0 for chunk k+1 from x (closes the ring) ----
template<bool REC, bool PRE>
__device__ __forceinline__ void l2_body(
    char* const smem, const int chunk, const int pre_chunk, const int tile,
    const float* __restrict__ x, const float* __restrict__ Pin, float* __restrict__ Pout,
    const f16* __restrict__ whh_h, const f16* __restrict__ wih0_h,
    const float* __restrict__ biasc, f16* __restrict__ st)
{
  char* const h_lds = smem;
  const int tid  = threadIdx.x;
  const int lane = tid & 63;
  const int wave = tid >> 6;
  const int m    = lane & 15;
  const int q    = lane >> 4;
  const int lo   = m * 16;
  const int slot  = chunk & 1;
  const int pslot = pre_chunk & 1;

  half8_t whh[2][8], wih0[2][2];
  float bias0[2];
#pragma unroll
  for (int jt = 0; jt < 2; ++jt) {
    const int j = wave * 32 + jt * 16 + m;
    if constexpr (PRE) {
      bias0[jt] = biasc[j];
#pragma unroll
      for (int c = 0; c < 2; ++c) wih0[jt][c] = *(const half8_t*)(wih0_h + j * 64 + c * 32 + q * 8);
    }
    if constexpr (REC) {
#pragma unroll
      for (int c = 0; c < 8; ++c) whh[jt][c] = *(const half8_t*)(whh_h + j * 256 + c * 32 + q * 8);
    }
  }
#pragma unroll
  for (int jt = 0; jt < 2; ++jt) {
    if constexpr (REC) {
#pragma unroll
      for (int c = 0; c < 8; ++c) pin(whh[jt][c]);
    }
    if constexpr (PRE) { pin(wih0[jt][0]); pin(wih0[jt][1]); }
  }

  float4_t pld[2][2];
  auto pload = [&](int tl, float4_t* d) {
    const int tn = (tl > TC - 1) ? (TC - 1) : tl;
    const char* gb = (const char*)Pin + poff(tile, slot, tn, wave * 32 + m, q);
    d[0] = *(const float4_t*)gb;
    d[1] = *(const float4_t*)(gb + 1024);
  };
  float4_t xp[2][4];
  auto xload = [&](int tl, float4_t* d) {
    const int tn = (tl > TC - 1) ? (TC - 1) : tl;
    const float* base = x + ((size_t)(tile * 16 + m) * Tsz + (pre_chunk * TC + tn)) * 64 + q * 8;
    d[0] = *(const float4_t*)base;        d[1] = *(const float4_t*)(base + 4);
    d[2] = *(const float4_t*)(base + 32); d[3] = *(const float4_t*)(base + 36);
  };

  if constexpr (REC) {
    if (chunk == 0)
      *(float4_t*)(h_lds + tid * 16) = float4_t{0.f, 0.f, 0.f, 0.f};
    else
      *(float4_t*)(h_lds + tid * 16) = *(const float4_t*)((const char*)st + tile * 8192 + tid * 16);
    pload(0, pld[0]); pload(1, pld[1]);
  }
  if constexpr (PRE) { xload(0, xp[0]); xload(1, xp[1]); }
  if constexpr (REC) BARRIER_LG;

#pragma unroll 4
  for (int tl = 0; tl < TC; ++tl) {
    if constexpr (REC) {
      char* cur = h_lds + (tl & 1) * 8192;
      char* nxt = h_lds + ((tl + 1) & 1) * 8192;
      half8_t hf[8];
#pragma unroll
      for (int c = 0; c < 8; ++c) hf[c] = *(const half8_t*)(cur + (c * 4 + q) * 256 + lo);
      float4_t acc[2];
#pragma unroll
      for (int jt = 0; jt < 2; ++jt) {
        float4_t a = pld[tl & 1][jt];
#pragma unroll
        for (int c = 0; c < 8; ++c)
          a = __builtin_amdgcn_mfma_f32_16x16x32_f16(hf[c], whh[jt][c], a, 0, 0, 0);
        acc[jt] = a;
      }
      pload(tl + 2, pld[tl & 1]);
#pragma unroll
      for (int jt = 0; jt < 2; ++jt) {
        const int j = wave * 32 + jt * 16 + m;
#pragma unroll
        for (int r = 0; r < 4; ++r) {
          const float e  = fast_exp2(acc[jt][r] * 2.8853900817779268f);
          const float hv = 1.0f - 2.0f * __builtin_amdgcn_rcpf(1.0f + e);
          const int b = q * 4 + r;
          *(f16*)(nxt + (j >> 3) * 256 + b * 16 + (j & 7) * 2) = (f16)hv;
        }
      }
    }
    if constexpr (PRE) {               // P0[pre_chunk][tl] = x @ Wih0^T + b0
      half8_t xf[2];
      const float4_t* xr = xp[tl & 1];
#pragma unroll
      for (int c = 0; c < 2; ++c)
#pragma unroll
        for (int u = 0; u < 8; ++u) xf[c][u] = (f16)xr[c * 2 + (u >> 2)][u & 3];
      xload(tl + 2, xp[tl & 1]);
#pragma unroll
      for (int jt = 0; jt < 2; ++jt) {
        float4_t b = {bias0[jt], bias0[jt], bias0[jt], bias0[jt]};
#pragma unroll
        for (int c = 0; c < 2; ++c)
          b = __builtin_amdgcn_mfma_f32_16x16x32_f16(xf[c], wih0[jt][c], b, 0, 0, 0);
        *(float4_t*)((char*)Pout + poff(tile, pslot, tl, wave * 32 + jt * 16 + m, q)) = b;
      }
    }
    if constexpr (REC) BARRIER_LG;
  }

  if constexpr (REC)
    *(float4_t*)((char*)st + tile * 8192 + tid * 16) = *(const float4_t*)(h_lds + tid * 16);
}

__global__ __launch_bounds__(512, 1)
void rnn_chunk_kernel(const float* __restrict__ x,
                      float* P0, float* P1, float* P2,
                      const f16* __restrict__ whh0h, const f16* __restrict__ whh1h,
                      const f16* __restrict__ whh2h, const f16* __restrict__ wih0h,
                      const f16* __restrict__ wih1h, const f16* __restrict__ wih2h,
                      const float* __restrict__ biasc,
                      f16* st0, f16* st1, f16* st2, int k)
{
  __shared__ __align__(16) char smem[16384];
  const int layer = blockIdx.x >> 5;
  const int tile  = blockIdx.x & 31;
  if (layer == 0) {
    if (k < NCH) rec01_body<0>(smem, k, tile, P0, P1, whh0h, wih1h, biasc, st0);
  } else if (layer == 1) {
    const int c = k - 1;
    if (c >= 0 && c < NCH) rec01_body<1>(smem, c, tile, P1, P2, whh1h, wih2h, biasc, st1);
  } else {
    const int c  = k - 2;
    const int pc = k + 1;                // P0 for chunk k+1 (consumed next dispatch)
    const bool rec = (c >= 0 && c < NCH);
    const bool pre = (pc < NCH);
    if (rec && pre)  l2_body<true,  true >(smem, c, pc, tile, x, P2, P0, whh2h, wih0h, biasc, st2);
    else if (rec)    l2_body<true,  false>(smem, c, pc, tile, x, P2, P0, whh2h, wih0h, biasc, st2);
    else if (pre)    l2_body<false, true >(smem, c, pc, tile, x, P2, P0, whh2h, wih0h, biasc, st2);
  }
}

// bootstrap: P0 for chunk 0 (before the pipeline starts)
__global__ __launch_bounds__(512, 1)
void pre0_kernel(const float* __restrict__ x, float* P0,
                 const f16* __restrict__ wih0h, const float* __restrict__ biasc)
{
  __shared__ __align__(16) char smem[16384];
  l2_body<false, true>(smem, 0, 0, blockIdx.x, x, nullptr, P0, nullptr, wih0h, biasc, nullptr);
}

// one-time weight convert f32->f16 + bias combine
__global__ void prep_kernel(const float* __restrict__ wih0, const float* __restrict__ whh0,
                            const float* __restrict__ bih0, const float* __restrict__ bhh0,
                            const float* __restrict__ wih1, const float* __restrict__ whh1,
                            const float* __restrict__ bih1, const float* __restrict__ bhh1,
                            const float* __restrict__ wih2, const float* __restrict__ whh2,
                            const float* __restrict__ bih2, const float* __restrict__ bhh2,
                            f16* wih0h, f16* whh0h, f16* wih1h, f16* whh1h,
                            f16* wih2h, f16* whh2h, float* biasc)
{
  const int i = blockIdx.x * 256 + threadIdx.x;
  if      (i < 16384)  wih0h[i]          = (f16)wih0[i];
  else if (i < 81920)  whh0h[i - 16384]  = (f16)whh0[i - 16384];
  else if (i < 147456) wih1h[i - 81920]  = (f16)wih1[i - 81920];
  else if (i < 212992) whh1h[i - 147456] = (f16)whh1[i - 147456];
  else if (i < 278528) wih2h[i - 212992] = (f16)wih2[i - 212992];
  else if (i < 344064) whh2h[i - 278528] = (f16)whh2[i - 278528];
  else if (i < 344320) biasc[i - 344064]       = bih0[i - 344064] + bhh0[i - 344064];
  else if (i < 344576) biasc[256 + i - 344320] = bih1[i - 344320] + bhh1[i - 344320];
  else if (i < 344832) biasc[512 + i - 344576] = bih2[i - 344576] + bhh2[i - 344576];
}

__global__ void fc_kernel(const f16* __restrict__ st2, const float* __restrict__ w_fc,
                          const float* __restrict__ b_fc, float* __restrict__ outp) {
  const int b = blockIdx.x;            // 512
  const int lane = threadIdx.x;        // 64
  const int tile = b >> 4, bl = b & 15;
  const int j = lane * 4;
  const char* hp = (const char*)st2 + tile * 8192 + (j >> 3) * 256 + bl * 16 + (j & 7) * 2;
  const half4_t hv = *(const half4_t*)hp;
  const float4_t w = *(const float4_t*)(w_fc + j);
  float s = (float)hv[0] * w[0] + (float)hv[1] * w[1] + (float)hv[2] * w[2] + (float)hv[3] * w[3];
#pragma unroll
  for (int off = 32; off > 0; off >>= 1) s += __shfl_down(s, off, 64);
  if (lane == 0) outp[b] = s + b_fc[0];
}

extern "C" void kernel_launch(void* const* d_in, const int* in_sizes, int n_in,
                              void* d_out, int out_size, void* d_ws, size_t ws_size,
                              hipStream_t stream) {
  const float* x     = (const float*)d_in[0];
  const float* w_ih0 = (const float*)d_in[1];
  const float* w_hh0 = (const float*)d_in[2];
  const float* b_ih0 = (const float*)d_in[3];
  const float* b_hh0 = (const float*)d_in[4];
  const float* w_ih1 = (const float*)d_in[5];
  const float* w_hh1 = (const float*)d_in[6];
  const float* b_ih1 = (const float*)d_in[7];
  const float* b_hh1 = (const float*)d_in[8];
  const float* w_ih2 = (const float*)d_in[9];
  const float* w_hh2 = (const float*)d_in[10];
  const float* b_ih2 = (const float*)d_in[11];
  const float* b_hh2 = (const float*)d_in[12];
  const float* w_fc  = (const float*)d_in[13];
  const float* b_fc  = (const float*)d_in[14];

  // ws layout, ~102 MB (round-3 proved ws_size >= 269,484,032):
  char* ws = (char*)d_ws;
  float* P0   = (float*)(ws);                   // 33,554,432 (32 tiles x 2 slots x 32 t x 16KB)
  float* P1   = (float*)(ws + 33554432);        // 33,554,432
  float* P2   = (float*)(ws + 67108864);        // 33,554,432
  f16* st0    = (f16*)(ws + 100663296);         //    262,144
  f16* st1    = (f16*)(ws + 100925440);         //    262,144
  f16* st2    = (f16*)(ws + 101187584);         //    262,144
  f16* wih0h  = (f16*)(ws + 101449728);         //     32,768
  f16* whh0h  = (f16*)(ws + 101482496);         //    131,072
  f16* wih1h  = (f16*)(ws + 101613568);         //    131,072
  f16* whh1h  = (f16*)(ws + 101744640);         //    131,072
  f16* wih2h  = (f16*)(ws + 101875712);         //    131,072
  f16* whh2h  = (f16*)(ws + 102006784);         //    131,072
  float* biasc = (float*)(ws + 102137856);      //      3,072

  prep_kernel<<<1347, 256, 0, stream>>>(w_ih0, w_hh0, b_ih0, b_hh0,
                                        w_ih1, w_hh1, b_ih1, b_hh1,
                                        w_ih2, w_hh2, b_ih2, b_hh2,
                                        wih0h, whh0h, wih1h, whh1h, wih2h, whh2h, biasc);
  pre0_kernel<<<32, 512, 0, stream>>>(x, P0, wih0h, biasc);
  // time-skewed pipeline: dispatch k = rec-L0(k) | rec-L1(k-1) | rec-L2(k-2)+pre0(k+1).
  // All cross-layer data (P only) flows across kernel-launch boundaries.
  for (int k = 0; k < NCH + 2; ++k)
    rnn_chunk_kernel<<<96, 512, 0, stream>>>(x, P0, P1, P2,
                                             whh0h, whh1h, whh2h,
                                             wih0h, wih1h, wih2h,
                                             biasc, st0, st1, st2, k);
  fc_kernel<<<512, 64, 0, stream>>>(st2, w_fc, b_fc, (float*)d_out);
}